// Round 1
// baseline (70.693 us; speedup 1.0000x reference)
//
#include <hip/hip_runtime.h>
#include <math.h>

// Gaussian KDE, n=12000.
// Pipeline (all deterministic, no float atomics):
//   0) memsetAsync counts
//   1) stats_k   (1 block): S1=sum(w), S2=sum(w^2), Sd=sum(d), Sd2=sum(d^2)
//   2) count_k   (188x4 blocks): packed (lt<<16|eq) rank counts via int atomics
//   3) pick_k    (1 block): select 4 order stats, compute h/scales, emit ejwj[]
//   4) kde_k     (188x4 blocks): partial[y][i] = sum_j w'_j * exp2(-(e_i-e_j)^2)
//   5) fin_k     : out[i] = log(sum_y partial[y][i] + 1e-10)

#define BLK 256
#define MAXJC 752   // per-wave j-chunk (multiple of 4 for float4 LDS reads)

#if defined(__has_builtin)
#if __has_builtin(__builtin_amdgcn_exp2f)
#define EXP2(x) __builtin_amdgcn_exp2f(x)
#endif
#endif
#ifndef EXP2
#define EXP2(x) exp2f(x)
#endif

__global__ __launch_bounds__(1024) void stats_k(const float* __restrict__ d,
                                                const float* __restrict__ w,
                                                float* __restrict__ ws, int n) {
    const int t = threadIdx.x;
    float s1 = 0.f, s2 = 0.f, sd = 0.f, sd2 = 0.f;
    for (int i = t; i < n; i += 1024) {
        float wv = w[i], dv = d[i];
        s1 += wv; s2 += wv * wv; sd += dv; sd2 += dv * dv;
    }
    // wave64 reduce
    for (int off = 32; off > 0; off >>= 1) {
        s1  += __shfl_down(s1,  off);
        s2  += __shfl_down(s2,  off);
        sd  += __shfl_down(sd,  off);
        sd2 += __shfl_down(sd2, off);
    }
    __shared__ float4 sred[16];
    const int wid = t >> 6, lane = t & 63;
    if (lane == 0) sred[wid] = make_float4(s1, s2, sd, sd2);
    __syncthreads();
    if (t == 0) {
        float4 a = sred[0];
        for (int k = 1; k < 16; ++k) {
            a.x += sred[k].x; a.y += sred[k].y; a.z += sred[k].z; a.w += sred[k].w;
        }
        ws[0] = a.x; ws[1] = a.y; ws[2] = a.z; ws[3] = a.w;
    }
}

// block: 64 i-values x 4 wave-chunks of JC j's. counts[i] += (lt<<16)|eq (int atomic).
__global__ __launch_bounds__(BLK) void count_k(const float* __restrict__ d,
                                               int* __restrict__ counts,
                                               int n, int JC) {
    __shared__ float sd_[4 * MAXJC];
    const int t = threadIdx.x;
    const int win = 4 * JC;
    const int jwin0 = blockIdx.y * win;
    for (int idx = t; idx < win; idx += BLK) {
        int jg = jwin0 + idx;
        // +inf: never < and never == any finite di -> contributes nothing
        sd_[idx] = (jg < n) ? d[jg] : __int_as_float(0x7f800000);
    }
    __syncthreads();
    const int lane = t & 63, c4 = t >> 6;
    const int i = blockIdx.x * 64 + lane;
    const float di = (i < n) ? d[i] : 0.f;
    int lt = 0, eq = 0;
    const float4* p4 = (const float4*)(sd_ + c4 * JC);  // 16B-aligned (JC%4==0)
    const int nq = JC >> 2;
    for (int jj = 0; jj < nq; ++jj) {
        float4 q = p4[jj];
        lt += (q.x < di) + (q.y < di) + (q.z < di) + (q.w < di);
        eq += (q.x == di) + (q.y == di) + (q.z == di) + (q.w == di);
    }
    if (i < n) atomicAdd(&counts[i], (lt << 16) | eq);
}

__global__ __launch_bounds__(1024) void pick_k(const float* __restrict__ d,
                                               const float* __restrict__ w,
                                               const int* __restrict__ counts,
                                               const float* __restrict__ stats,
                                               float2* __restrict__ ejwj, int n) {
    __shared__ float sp[4];      // values at ranks l25,u25,l75,u75
    __shared__ float sparams[2]; // r, wscale
    const int t = threadIdx.x;

    const double p25 = 0.25 * (double)(n - 1);
    const double p75 = 0.75 * (double)(n - 1);
    const int l25 = (int)p25, l75 = (int)p75;
    const int u25 = (l25 + 1 < n) ? l25 + 1 : l25;
    const int u75 = (l75 + 1 < n) ? l75 + 1 : l75;
    const int tk0 = l25, tk1 = u25, tk2 = l75, tk3 = u75;

    for (int i = t; i < n; i += 1024) {
        int c = counts[i];
        int lt = c >> 16, eq = c & 0xFFFF;
        int hi = lt + eq;
        if (lt <= tk0 && tk0 < hi) sp[0] = d[i];
        if (lt <= tk1 && tk1 < hi) sp[1] = d[i];
        if (lt <= tk2 && tk2 < hi) sp[2] = d[i];
        if (lt <= tk3 && tk3 < hi) sp[3] = d[i];
    }
    __syncthreads();
    if (t == 0) {
        double s1 = stats[0], s2 = stats[1], sd = stats[2], sd2 = stats[3];
        double neff = s1 * s1 / s2;
        double var  = (sd2 - sd * sd / (double)n) / ((double)n - 1.0);
        double sdev = sqrt(var);
        double f25 = p25 - (double)l25, f75 = p75 - (double)l75;
        double q25 = (double)sp[0] + f25 * ((double)sp[1] - (double)sp[0]);
        double q75 = (double)sp[2] + f75 * ((double)sp[3] - (double)sp[2]);
        double iqr = q75 - q25;
        double sig = fmin(sdev, iqr / 1.34);
        double h = 0.9 * sig * pow(neff, -0.2);
        // exp(-0.5*((di-dj)/h)^2) = exp2(-(r*di - r*dj)^2), r = sqrt(0.5*log2(e))/h
        double r = sqrt(0.5 * 1.4426950408889634) / h;
        double wsc = 1.0 / (h * sqrt(6.283185307179586) * s1); // inv_norm / S1
        sparams[0] = (float)r;
        sparams[1] = (float)wsc;
    }
    __syncthreads();
    const float r = sparams[0], wsc = sparams[1];
    for (int j = t; j < n; j += 1024)
        ejwj[j] = make_float2(d[j] * r, w[j] * wsc);
}

__global__ __launch_bounds__(BLK) void kde_k(const float2* __restrict__ ejwj,
                                             float* __restrict__ partial,
                                             int n, int JC, int nmax) {
    __shared__ float2 sj[4 * MAXJC];  // 24 KiB
    const int t = threadIdx.x;
    const int win = 4 * JC;
    const int jwin0 = blockIdx.y * win;
    for (int idx = t; idx < win; idx += BLK) {
        int jg = jwin0 + idx;
        sj[idx] = (jg < n) ? ejwj[jg] : make_float2(0.f, 0.f);  // w=0 -> no contribution
    }
    __syncthreads();
    const int lane = t & 63, c4 = t >> 6;
    const int i = blockIdx.x * 64 + lane;
    const float ei = (i < n) ? ejwj[i].x : 0.f;
    const float4* p4 = (const float4*)(sj + c4 * JC);  // (e0,w0,e1,w1), 16B-aligned
    float acc0 = 0.f, acc1 = 0.f;
    const int nq = JC >> 1;
    for (int jj = 0; jj < nq; ++jj) {
        float4 q = p4[jj];
        float da = ei - q.x;
        float db = ei - q.z;
        acc0 += q.y * EXP2(-(da * da));
        acc1 += q.w * EXP2(-(db * db));
    }
    __syncthreads();
    float* red = (float*)sj;
    red[t] = acc0 + acc1;
    __syncthreads();
    if (t < 64) {
        int ii = blockIdx.x * 64 + t;
        if (ii < n) {
            float s = red[t] + red[t + 64] + red[t + 128] + red[t + 192];
            partial[blockIdx.y * nmax + ii] = s;
        }
    }
}

__global__ void fin_k(const float* __restrict__ partial, float* __restrict__ out,
                      int n, int nmax) {
    int i = blockIdx.x * blockDim.x + threadIdx.x;
    if (i < n) {
        float p = partial[i] + partial[nmax + i] + partial[2 * nmax + i] + partial[3 * nmax + i];
        out[i] = logf(p + 1e-10f);
    }
}

extern "C" void kernel_launch(void* const* d_in, const int* in_sizes, int n_in,
                              void* d_out, int out_size, void* d_ws, size_t ws_size,
                              hipStream_t stream) {
    const float* d = (const float*)d_in[0];
    const float* w = (const float*)d_in[1];
    float* out = (float*)d_out;
    const int n = in_sizes[0];

    const int nmax = ((n + 63) / 64) * 64;   // 12032
    const int JC   = 4 * ((n + 63) / 64);    // 752 (<= MAXJC)

    // ws layout (floats): [0..3] stats | [4..4+nmax) counts(int) | 4 picks spare |
    //                     params spare | ejwj float2[nmax] | partial[4][nmax]
    float* wsf     = (float*)d_ws;
    int*   counts  = (int*)(wsf + 4);
    float2* ejwj   = (float2*)(wsf + 16 + nmax);       // byte offset (16+nmax)*4, 8B-aligned
    float* partial = wsf + 16 + 3 * nmax;

    hipMemsetAsync(counts, 0, (size_t)nmax * sizeof(int), stream);
    stats_k<<<1, 1024, 0, stream>>>(d, w, wsf, n);

    dim3 grid(nmax / 64, 4);
    count_k<<<grid, BLK, 0, stream>>>(d, counts, n, JC);
    pick_k<<<1, 1024, 0, stream>>>(d, w, counts, wsf, ejwj, n);
    kde_k<<<grid, BLK, 0, stream>>>(ejwj, partial, n, JC, nmax);
    fin_k<<<(n + 255) / 256, 256, 0, stream>>>(partial, out, n, nmax);
}

// Round 2
// 63.197 us; speedup vs baseline: 1.1186x; 1.1186x over previous
//
#include <hip/hip_runtime.h>
#include <math.h>

// Gaussian KDE, n=12000.
// Pipeline (deterministic, no atomics, no memset):
//   1) count_k (188x4 blocks): counts[y*nmax+i] = packed (lt<<16|eq) over y's j-window
//   2) pick_k  (1 block): stats sums + select 4 order stats + compute h/scales, emit ejwj[]
//   3) kde_k   (188x4 blocks): partial[y*nmax+i] = sum_{j in window} w'_j * exp2(-(e_i-e_j)^2)
//   4) fin_k   : out[i] = log(sum_y partial[y][i] + 1e-10)

#define BLK 256
#define MAXJC 752   // per-wave j-chunk (multiple of 4 for float4 LDS reads)

#if defined(__has_builtin)
#if __has_builtin(__builtin_amdgcn_exp2f)
#define EXP2(x) __builtin_amdgcn_exp2f(x)
#endif
#endif
#ifndef EXP2
#define EXP2(x) exp2f(x)
#endif

// block: 64 i-values x 4 wave-chunks of JC j's. One packed partial per (i, y).
__global__ __launch_bounds__(BLK) void count_k(const float* __restrict__ d,
                                               int* __restrict__ counts,
                                               int n, int JC, int nmax) {
    __shared__ float sd_[4 * MAXJC];
    const int t = threadIdx.x;
    const int win = 4 * JC;
    const int jwin0 = blockIdx.y * win;
    for (int idx = t; idx < win; idx += BLK) {
        int jg = jwin0 + idx;
        // +inf: never < and never == any finite di -> contributes nothing
        sd_[idx] = (jg < n) ? d[jg] : __int_as_float(0x7f800000);
    }
    __syncthreads();
    const int lane = t & 63, c4 = t >> 6;
    const int i = blockIdx.x * 64 + lane;
    const float di = (i < n) ? d[i] : 0.f;
    int lt = 0, eq = 0;
    const float4* p4 = (const float4*)(sd_ + c4 * JC);  // 16B-aligned (JC%4==0)
    const int nq = JC >> 2;
    for (int jj = 0; jj < nq; ++jj) {
        float4 q = p4[jj];
        lt += (q.x < di) + (q.y < di) + (q.z < di) + (q.w < di);
        eq += (q.x == di) + (q.y == di) + (q.z == di) + (q.w == di);
    }
    // combine the 4 wave-chunks of this block via LDS, then one write per i
    __syncthreads();
    int* red = (int*)sd_;
    red[t] = (lt << 16) | eq;
    __syncthreads();
    if (t < 64 && i < n) {
        int s = red[t] + red[t + 64] + red[t + 128] + red[t + 192];
        counts[blockIdx.y * nmax + blockIdx.x * 64 + t] = s;
    }
}

__global__ __launch_bounds__(1024) void pick_k(const float* __restrict__ d,
                                               const float* __restrict__ w,
                                               const int* __restrict__ counts,
                                               float2* __restrict__ ejwj,
                                               int n, int nmax) {
    __shared__ float sp[4];      // values at ranks l25,u25,l75,u75
    __shared__ float sparams[2]; // r, wscale
    __shared__ float4 sred[16];
    const int t = threadIdx.x;

    const double p25 = 0.25 * (double)(n - 1);
    const double p75 = 0.75 * (double)(n - 1);
    const int l25 = (int)p25, l75 = (int)p75;
    const int u25 = (l25 + 1 < n) ? l25 + 1 : l25;
    const int u75 = (l75 + 1 < n) ? l75 + 1 : l75;

    float s1 = 0.f, s2 = 0.f, sd = 0.f, sd2 = 0.f;
    for (int i = t; i < n; i += 1024) {
        float wv = w[i], dv = d[i];
        s1 += wv; s2 += wv * wv; sd += dv; sd2 += dv * dv;
        // packed sum of 4 y-partials: lt,eq each <= n < 2^16 so no carry between fields
        int c = counts[i] + counts[nmax + i] + counts[2 * nmax + i] + counts[3 * nmax + i];
        int lt = c >> 16, eq = c & 0xFFFF;
        int hi = lt + eq;
        if (lt <= l25 && l25 < hi) sp[0] = dv;
        if (lt <= u25 && u25 < hi) sp[1] = dv;
        if (lt <= l75 && l75 < hi) sp[2] = dv;
        if (lt <= u75 && u75 < hi) sp[3] = dv;
    }
    for (int off = 32; off > 0; off >>= 1) {
        s1  += __shfl_down(s1,  off);
        s2  += __shfl_down(s2,  off);
        sd  += __shfl_down(sd,  off);
        sd2 += __shfl_down(sd2, off);
    }
    const int wid = t >> 6, lane = t & 63;
    if (lane == 0) sred[wid] = make_float4(s1, s2, sd, sd2);
    __syncthreads();
    if (t == 0) {
        float4 a = sred[0];
        for (int k = 1; k < 16; ++k) {
            a.x += sred[k].x; a.y += sred[k].y; a.z += sred[k].z; a.w += sred[k].w;
        }
        double S1 = a.x, S2 = a.y, Sd = a.z, Sd2 = a.w;
        double neff = S1 * S1 / S2;
        double var  = (Sd2 - Sd * Sd / (double)n) / ((double)n - 1.0);
        double sdev = sqrt(var);
        double f25 = p25 - (double)l25, f75 = p75 - (double)l75;
        double q25 = (double)sp[0] + f25 * ((double)sp[1] - (double)sp[0]);
        double q75 = (double)sp[2] + f75 * ((double)sp[3] - (double)sp[2]);
        double iqr = q75 - q25;
        double sig = fmin(sdev, iqr / 1.34);
        double h = 0.9 * sig * pow(neff, -0.2);
        // exp(-0.5*((di-dj)/h)^2) = exp2(-(r*di - r*dj)^2), r = sqrt(0.5*log2(e))/h
        double r = sqrt(0.5 * 1.4426950408889634) / h;
        double wsc = 1.0 / (h * sqrt(6.283185307179586) * S1); // inv_norm / S1
        sparams[0] = (float)r;
        sparams[1] = (float)wsc;
    }
    __syncthreads();
    const float r = sparams[0], wsc = sparams[1];
    for (int j = t; j < n; j += 1024)
        ejwj[j] = make_float2(d[j] * r, w[j] * wsc);
}

__global__ __launch_bounds__(BLK) void kde_k(const float2* __restrict__ ejwj,
                                             float* __restrict__ partial,
                                             int n, int JC, int nmax) {
    __shared__ float2 sj[4 * MAXJC];  // 24 KiB
    const int t = threadIdx.x;
    const int win = 4 * JC;
    const int jwin0 = blockIdx.y * win;
    for (int idx = t; idx < win; idx += BLK) {
        int jg = jwin0 + idx;
        sj[idx] = (jg < n) ? ejwj[jg] : make_float2(0.f, 0.f);  // w=0 -> no contribution
    }
    __syncthreads();
    const int lane = t & 63, c4 = t >> 6;
    const int i = blockIdx.x * 64 + lane;
    const float ei = (i < n) ? ejwj[i].x : 0.f;
    const float4* p4 = (const float4*)(sj + c4 * JC);  // (e0,w0,e1,w1), 16B-aligned
    float acc0 = 0.f, acc1 = 0.f;
    const int nq = JC >> 1;
    for (int jj = 0; jj < nq; ++jj) {
        float4 q = p4[jj];
        float da = ei - q.x;
        float db = ei - q.z;
        acc0 += q.y * EXP2(-(da * da));
        acc1 += q.w * EXP2(-(db * db));
    }
    __syncthreads();
    float* red = (float*)sj;
    red[t] = acc0 + acc1;
    __syncthreads();
    if (t < 64) {
        int ii = blockIdx.x * 64 + t;
        if (ii < n) {
            float s = red[t] + red[t + 64] + red[t + 128] + red[t + 192];
            partial[blockIdx.y * nmax + ii] = s;
        }
    }
}

__global__ void fin_k(const float* __restrict__ partial, float* __restrict__ out,
                      int n, int nmax) {
    int i = blockIdx.x * blockDim.x + threadIdx.x;
    if (i < n) {
        float p = partial[i] + partial[nmax + i] + partial[2 * nmax + i] + partial[3 * nmax + i];
        out[i] = logf(p + 1e-10f);
    }
}

extern "C" void kernel_launch(void* const* d_in, const int* in_sizes, int n_in,
                              void* d_out, int out_size, void* d_ws, size_t ws_size,
                              hipStream_t stream) {
    const float* d = (const float*)d_in[0];
    const float* w = (const float*)d_in[1];
    float* out = (float*)d_out;
    const int n = in_sizes[0];

    const int nmax = ((n + 63) / 64) * 64;   // 12032
    const int JC   = 4 * ((n + 63) / 64);    // 752 (<= MAXJC)

    // ws layout (floats): counts int[4*nmax] | ejwj float2[nmax] | partial float[4*nmax]
    float* wsf     = (float*)d_ws;
    int*   counts  = (int*)wsf;
    float2* ejwj   = (float2*)(wsf + 4 * nmax);   // 8B-aligned (4*nmax*4 bytes)
    float* partial = wsf + 6 * nmax;

    dim3 grid(nmax / 64, 4);
    count_k<<<grid, BLK, 0, stream>>>(d, counts, n, JC, nmax);
    pick_k<<<1, 1024, 0, stream>>>(d, w, counts, ejwj, n, nmax);
    kde_k<<<grid, BLK, 0, stream>>>(ejwj, partial, n, JC, nmax);
    fin_k<<<(n + 255) / 256, 256, 0, stream>>>(partial, out, n, nmax);
}